// Round 2
// baseline (615.136 us; speedup 1.0000x reference)
//
#include <hip/hip_runtime.h>
#include <stdint.h>

#define N      8192
#define NW32   256          // N/32 words per adj row
#define FEAT   512
#define HID    64
#define NH     4
#define C1     256          // NH*HID
#define PCH    65           // accA per-head stride (64 data + Z at col 64)
#define TC     260          // NH*PCH
#define NCLS   16
#define C2     32           // accB stride (16 data + Z at col 16)
#define IPB    8            // rows per block in k1
#define LOG2E  1.44269504f

typedef __attribute__((ext_vector_type(8))) short bf16x8;
typedef __attribute__((ext_vector_type(4))) float f32x4;

__device__ __forceinline__ float b2f(uint16_t u){
  uint32_t x = ((uint32_t)u) << 16;
  return __builtin_bit_cast(float, x);
}
__device__ __forceinline__ uint16_t f2b(float f){
  uint32_t x = __builtin_bit_cast(uint32_t, f);
  uint32_t r = (x + 0x7fffu + ((x >> 16) & 1u)) >> 16;
  return (uint16_t)r;
}
__device__ __forceinline__ float lrelu(float v, float a){ return fmaxf(v, a * v); }
__device__ __forceinline__ float fexp2(float x){
#if __has_builtin(__builtin_amdgcn_exp2f)
  return __builtin_amdgcn_exp2f(x);
#else
  return exp2f(x);
#endif
}
__device__ __forceinline__ uint32_t pk_bf16(float lo, float hi){
  uint32_t r;
  asm("v_cvt_pk_bf16_f32 %0, %1, %2" : "=v"(r) : "v"(lo), "v"(hi));
  return r;
}

// build one A-fragment (8 scores) fully in registers; masked by 8 adjacency bits
__device__ __forceinline__ bf16x8 mk_frag(float f1v, float4 fa, float4 fb,
                                          uint32_t ub, float& dsum){
  float e0, e1, e2, e3, e4, e5, e6, e7, s;
  s = f1v + fa.x; e0 = fexp2(fmaxf(s, 0.2f * s)); if (!(ub &   1u)) e0 = 0.f;
  s = f1v + fa.y; e1 = fexp2(fmaxf(s, 0.2f * s)); if (!(ub &   2u)) e1 = 0.f;
  s = f1v + fa.z; e2 = fexp2(fmaxf(s, 0.2f * s)); if (!(ub &   4u)) e2 = 0.f;
  s = f1v + fa.w; e3 = fexp2(fmaxf(s, 0.2f * s)); if (!(ub &   8u)) e3 = 0.f;
  s = f1v + fb.x; e4 = fexp2(fmaxf(s, 0.2f * s)); if (!(ub &  16u)) e4 = 0.f;
  s = f1v + fb.y; e5 = fexp2(fmaxf(s, 0.2f * s)); if (!(ub &  32u)) e5 = 0.f;
  s = f1v + fb.z; e6 = fexp2(fmaxf(s, 0.2f * s)); if (!(ub &  64u)) e6 = 0.f;
  s = f1v + fb.w; e7 = fexp2(fmaxf(s, 0.2f * s)); if (!(ub & 128u)) e7 = 0.f;
  dsum += ((e0 + e1) + (e2 + e3)) + ((e4 + e5) + (e6 + e7));
  union { uint32_t u[4]; bf16x8 v; } r;
  r.u[0] = pk_bf16(e0, e1);
  r.u[1] = pk_bf16(e2, e3);
  r.u[2] = pk_bf16(e4, e5);
  r.u[3] = pk_bf16(e6, e7);
  return r.v;
}

// ---------------------------------------------------------------- kp: pack adj int32 -> bitmask (8 MB)
__global__ __launch_bounds__(256) void kp_pack(const int* __restrict__ adj,
                                               unsigned long long* __restrict__ adjP64){
  int t = threadIdx.x;
  int lane = t & 63;
  int wg = blockIdx.x * 4 + (t >> 6);          // 0..8191 global wave id
  for (int it = 0; it < 128; ++it){
    size_t c = (size_t)it * 8192 + wg;         // 64-int chunk index
    int v = adj[c * 64 + lane];
    unsigned long long m = __ballot(v > 0);
    if (lane == 0) adjP64[c] = m;
  }
}

// ---------------------------------------------------------------- k0: Wh -> WhT[k][cc][f]  (fp32)
__global__ void k0_wht(const float* __restrict__ Wh, float* __restrict__ WhT){
  int idx = blockIdx.x * 256 + threadIdx.x;
  int k = idx >> 15;
  int r = idx & 32767;
  int cc = r >> 9, f = r & 511;
  WhT[idx] = Wh[k * 32768 + f * 64 + cc];
}

// ---------------------------------------------------------------- k1: H = x @ Wh  (+ f1,f2 pre-scaled by log2e)
__global__ __launch_bounds__(256) void k1_h(const float* __restrict__ x,
    const float* __restrict__ WhT, const float* __restrict__ ah,
    uint16_t* __restrict__ H, float* __restrict__ f1, float* __restrict__ f2)
{
  __shared__ float4 xs[IPB][128];
  int t = threadIdx.x;
  int i0 = blockIdx.x * IPB;
  for (int r = t; r < IPB * 128; r += 256){
    int ii = r >> 7, o = r & 127;
    xs[ii][o] = *((const float4*)(x + (size_t)(i0 + ii) * FEAT) + o);
  }
  __syncthreads();
  int k = t >> 6, cc = t & 63;
  const float4* wrow = (const float4*)(WhT + k * 32768 + cc * 512);
  float acc[IPB] = {};
  for (int f4 = 0; f4 < 128; ++f4){
    float4 wv = wrow[f4];
    #pragma unroll
    for (int ii = 0; ii < IPB; ++ii){
      float4 xv = xs[ii][f4];
      acc[ii] += xv.x * wv.x + xv.y * wv.y + xv.z * wv.z + xv.w * wv.w;
    }
  }
  float a1 = ah[k * 128 + cc], a2 = ah[k * 128 + 64 + cc];
  #pragma unroll
  for (int ii = 0; ii < IPB; ++ii){
    int i = i0 + ii;
    H[(size_t)i * C1 + t] = f2b(acc[ii]);
    float c1v = acc[ii] * a1, c2v = acc[ii] * a2;
    #pragma unroll
    for (int off = 32; off; off >>= 1){
      c1v += __shfl_down(c1v, off);
      c2v += __shfl_down(c2v, off);
    }
    if (cc == 0){ f1[k * N + i] = c1v * LOG2E; f2[k * N + i] = c2v * LOG2E; }
  }
}

// ---------------------------------------------------------------- k2a: HT[k][p<64][i] = H[i][k*64+p]
__global__ void k2a_htT(const uint16_t* __restrict__ H, uint16_t* __restrict__ HT){
  __shared__ uint16_t tile[64][65];
  int bid = blockIdx.x;
  int k = bid & 3, it = bid >> 2;
  int i0 = it * 64;
  int t = threadIdx.x;
  #pragma unroll
  for (int r = 0; r < 4; ++r){
    int ii = r * 16 + (t >> 4);
    int pp = (t & 15) * 4;
    uint2 v = *(const uint2*)(H + (size_t)(i0 + ii) * C1 + k * 64 + pp);
    const uint16_t* s = (const uint16_t*)&v;
    tile[pp + 0][ii] = s[0]; tile[pp + 1][ii] = s[1];
    tile[pp + 2][ii] = s[2]; tile[pp + 3][ii] = s[3];
  }
  __syncthreads();
  #pragma unroll
  for (int r = 0; r < 4; ++r){
    int pp = r * 16 + (t >> 4);
    int ii = (t & 15) * 4;
    uint2 v;
    uint16_t* s = (uint16_t*)&v;
    s[0] = tile[pp][ii + 0]; s[1] = tile[pp][ii + 1];
    s[2] = tile[pp][ii + 2]; s[3] = tile[pp][ii + 3];
    *(uint2*)(HT + (size_t)k * (64 * N) + (size_t)pp * N + i0 + ii) = v;
  }
}

// ---------------------------------------------------------------- k3: phase-A attention (register-P, 1 barrier/jc)
#define K3_BODY(JC, CUR, NXT)                                                   \
  {                                                                             \
    *(uint4*)&Hl[(JC) & 1][p0][o40 * 8] = h##CUR##0;                            \
    *(uint4*)&Hl[(JC) & 1][p1][o40 * 8] = h##CUR##1;                            \
    const int gjn = js * 2048 + (((JC) + 1) & 63) * 32;                         \
    h##NXT##0 = *(const uint4*)(src0 + gjn);                                    \
    h##NXT##1 = *(const uint4*)(src1 + gjn);                                    \
    w##NXT##0 = adjP[arow0 + (gjn >> 5)];                                       \
    w##NXT##1 = adjP[arow1 + (gjn >> 5)];                                       \
    f##NXT##0 = *(const float4*)(f2h + gjn + 8 * q);                            \
    f##NXT##1 = *(const float4*)(f2h + gjn + 8 * q + 4);                        \
    bf16x8 af0 = mk_frag(f1v0, f##CUR##0, f##CUR##1,                            \
                         (w##CUR##0 >> (8 * q)) & 255u, dsum0);                 \
    bf16x8 af1 = mk_frag(f1v1, f##CUR##0, f##CUR##1,                            \
                         (w##CUR##1 >> (8 * q)) & 255u, dsum1);                 \
    __syncthreads();                                                            \
    _Pragma("unroll")                                                           \
    for (int ct = 0; ct < 4; ++ct){                                             \
      bf16x8 bfr = *(const bf16x8*)&Hl[(JC) & 1][head * 64 + ct * 16 + m][q * 8]; \
      acc[0][ct] = __builtin_amdgcn_mfma_f32_16x16x32_bf16(af0, bfr, acc[0][ct], 0, 0, 0); \
      acc[1][ct] = __builtin_amdgcn_mfma_f32_16x16x32_bf16(af1, bfr, acc[1][ct], 0, 0, 0); \
    }                                                                           \
  }

__global__ __launch_bounds__(512, 4) void k3_attA(const uint32_t* __restrict__ adjP,
    const uint16_t* __restrict__ HT, const float* __restrict__ f1,
    const float* __restrict__ f2, float* __restrict__ accA)
{
  __shared__ uint16_t Hl[2][256][40];

  const int t = threadIdx.x;
  const int ibl = blockIdx.x >> 2;
  const int js = blockIdx.x & 3;
  const int gi0 = ibl * 64;

  const int lane = t & 63;
  const int w    = t >> 6;          // wave 0..7
  const int head = w >> 1;
  const int ith  = w & 1;
  const int m    = lane & 15;
  const int q    = lane >> 4;

  // staging: 256 rows x 4 uint4 chunks = 1024; 512 threads -> 2 each
  const int p0 = t >> 2, o40 = t & 3;
  const int p1 = p0 + 128;
  const uint16_t* src0 = HT + (size_t)p0 * N + o40 * 8;
  const uint16_t* src1 = HT + (size_t)p1 * N + o40 * 8;

  const int row0 = gi0 + ith * 32 + m;        // itl = 0 rows
  const int arow0 = row0 * NW32;
  const int arow1 = (row0 + 16) * NW32;       // itl = 1 rows
  const float* f2h = f2 + (size_t)head * N;
  const float f1v0 = f1[(size_t)head * N + row0];
  const float f1v1 = f1[(size_t)head * N + row0 + 16];

  f32x4 acc[2][4] = {};
  float dsum0 = 0.f, dsum1 = 0.f;

  uint4 hA0, hA1, hB0, hB1;
  uint32_t wA0, wA1, wB0, wB1;
  float4 fA0, fA1, fB0, fB1;

  {   // prologue: jc = 0
    const int gj0 = js * 2048;
    hA0 = *(const uint4*)(src0 + gj0);
    hA1 = *(const uint4*)(src1 + gj0);
    wA0 = adjP[arow0 + (gj0 >> 5)];
    wA1 = adjP[arow1 + (gj0 >> 5)];
    fA0 = *(const float4*)(f2h + gj0 + 8 * q);
    fA1 = *(const float4*)(f2h + gj0 + 8 * q + 4);
  }

  for (int jc = 0; jc < 64; jc += 2){
    K3_BODY(jc,     A, B)
    K3_BODY(jc + 1, B, A)
  }

  #pragma unroll
  for (int itl = 0; itl < 2; ++itl)
    #pragma unroll
    for (int ct = 0; ct < 4; ++ct)
      #pragma unroll
      for (int reg = 0; reg < 4; ++reg){
        int gi = gi0 + ith * 32 + itl * 16 + q * 4 + reg;
        accA[((size_t)js * N + gi) * TC + head * PCH + ct * 16 + m] = acc[itl][ct][reg];
      }
  {
    float v0 = dsum0, v1 = dsum1;
    v0 += __shfl_xor(v0, 16); v0 += __shfl_xor(v0, 32);
    v1 += __shfl_xor(v1, 16); v1 += __shfl_xor(v1, 32);
    if (q == 0){
      accA[((size_t)js * N + row0)      * TC + head * PCH + 64] = v0;
      accA[((size_t)js * N + row0 + 16) * TC + head * PCH + 64] = v1;
    }
  }
}

// ---------------------------------------------------------------- k4: reduce partials -> xcat (lrelu 0.01)
__global__ void k4_redA(const float* __restrict__ accA, uint16_t* __restrict__ xcat){
  int i = blockIdx.x;
  int t = threadIdx.x;
  int k = t >> 6, cc = t & 63;
  size_t base = (size_t)i * TC + k * PCH;
  float v = 0.f, Z = 0.f;
  #pragma unroll
  for (int js = 0; js < 4; ++js){
    const float* p = accA + (size_t)js * N * TC + base;
    v += p[cc];
    Z += p[64];
  }
  float r = v / Z;
  xcat[(size_t)i * C1 + t] = f2b(lrelu(r, 0.01f));
}

// ---------------------------------------------------------------- k5: h2 = xcat@Wo, f1o/f2o (scaled), h2T rows 0..15
__global__ __launch_bounds__(256) void k5_h2(const uint16_t* __restrict__ xcat,
    const float* __restrict__ Wo, const float* __restrict__ ao,
    uint16_t* __restrict__ h2T, float* __restrict__ f1o, float* __restrict__ f2o)
{
  __shared__ uint16_t xs[16][256];
  int t = threadIdx.x;
  int i0 = blockIdx.x * 16;
  #pragma unroll
  for (int r = 0; r < 2; ++r){
    int idx = t + 256 * r;
    int ii = idx >> 5, o4 = idx & 31;
    *(uint4*)&xs[ii][o4 * 8] = *(const uint4*)(xcat + (size_t)(i0 + ii) * C1 + o4 * 8);
  }
  __syncthreads();
  int ii = t >> 4, c = t & 15;
  float acc = 0.f;
  for (int f = 0; f < 256; ++f)
    acc += b2f(xs[ii][f]) * Wo[f * 16 + c];
  int i = i0 + ii;
  h2T[(size_t)c * N + i] = f2b(acc);
  float u1 = acc * ao[c];
  float u2 = acc * ao[16 + c];
  #pragma unroll
  for (int off = 8; off; off >>= 1){
    u1 += __shfl_down(u1, off, 16);
    u2 += __shfl_down(u2, off, 16);
  }
  if (c == 0){ f1o[i] = u1 * LOG2E; f2o[i] = u2 * LOG2E; }
}

// ---------------------------------------------------------------- k6: phase-B attention (register-P, 1 barrier/jc)
#define K6_BODY(JC, CUR, NXT)                                                   \
  {                                                                             \
    if (stg) *(uint4*)&Hl[(JC) & 1][p0][o40 * 8] = h##CUR;                      \
    const int gjn = js * 1024 + (((JC) + 1) & 31) * 32;                         \
    if (stg) h##NXT = *(const uint4*)(h2T + (size_t)p0 * N + gjn + o40 * 8);    \
    w##NXT = adjP[arow + (gjn >> 5)];                                           \
    f##NXT##0 = *(const float4*)(f2o + gjn + 8 * q);                            \
    f##NXT##1 = *(const float4*)(f2o + gjn + 8 * q + 4);                        \
    bf16x8 af = mk_frag(f1v, f##CUR##0, f##CUR##1,                              \
                        (w##CUR >> (8 * q)) & 255u, dsum);                      \
    __syncthreads();                                                            \
    bf16x8 b0 = *(const bf16x8*)&Hl[(JC) & 1][m][q * 8];                        \
    acc0 = __builtin_amdgcn_mfma_f32_16x16x32_bf16(af, b0, acc0, 0, 0, 0);      \
  }

__global__ __launch_bounds__(256) void k6_attB(const uint32_t* __restrict__ adjP,
    const uint16_t* __restrict__ h2T, const float* __restrict__ f1o,
    const float* __restrict__ f2o, float* __restrict__ accB)
{
  __shared__ uint16_t Hl[2][16][40];

  const int t = threadIdx.x;
  const int ibl = blockIdx.x >> 3;
  const int js = blockIdx.x & 7;
  const int gi0 = ibl * 64;

  const int lane = t & 63;
  const int w = t >> 6;             // wave 0..3
  const int m = lane & 15;
  const int q = lane >> 4;

  const int p0 = t >> 2, o40 = t & 3;
  const bool stg = (t < 64);        // 16 rows x 4 chunks

  const int row = gi0 + w * 16 + m;
  const int arow = row * NW32;
  const float f1v = f1o[row];

  f32x4 acc0 = {0.f, 0.f, 0.f, 0.f};
  float dsum = 0.f;

  uint4 hA = {}, hB = {};
  uint32_t wA, wB;
  float4 fA0, fA1, fB0, fB1;

  {   // prologue: jc = 0
    const int gj0 = js * 1024;
    if (stg) hA = *(const uint4*)(h2T + (size_t)p0 * N + gj0 + o40 * 8);
    wA = adjP[arow + (gj0 >> 5)];
    fA0 = *(const float4*)(f2o + gj0 + 8 * q);
    fA1 = *(const float4*)(f2o + gj0 + 8 * q + 4);
  }

  for (int jc = 0; jc < 32; jc += 2){
    K6_BODY(jc,     A, B)
    K6_BODY(jc + 1, B, A)
  }

  #pragma unroll
  for (int reg = 0; reg < 4; ++reg){
    int gi = gi0 + w * 16 + q * 4 + reg;
    accB[((size_t)js * N + gi) * C2 + m] = acc0[reg];
  }
  {
    float v = dsum;
    v += __shfl_xor(v, 16); v += __shfl_xor(v, 32);
    if (q == 0)
      accB[((size_t)js * N + row) * C2 + 16] = v;
  }
}

// ---------------------------------------------------------------- k7: reduce -> out (fp32)
__global__ void k7_redB(const float* __restrict__ accB, float* __restrict__ out){
  int idx = blockIdx.x * 256 + threadIdx.x;   // 131072
  int i = idx >> 4, c = idx & 15;
  float v = 0.f, Z = 0.f;
  #pragma unroll
  for (int js = 0; js < 8; ++js){
    const float* p = accB + ((size_t)js * N + i) * C2;
    v += p[c];
    Z += p[16];
  }
  out[idx] = v / Z;
}

// ================================================================ launch
extern "C" void kernel_launch(void* const* d_in, const int* in_sizes, int n_in,
                              void* d_out, int out_size, void* d_ws, size_t ws_size,
                              hipStream_t stream)
{
  const float* x   = (const float*)d_in[0];
  const int*   adj = (const int*)d_in[1];
  const float* Wh  = (const float*)d_in[2];
  const float* ah  = (const float*)d_in[3];
  const float* Wo  = (const float*)d_in[4];
  const float* ao  = (const float*)d_in[5];
  float* out = (float*)d_out;

  char* ws = (char*)d_ws;
  float*    WhT  = (float*)   (ws);                 // 512 KB
  uint16_t* H    = (uint16_t*)(ws + 524288);        // 4 MB    [8192][256] bf16
  uint16_t* HT   = (uint16_t*)(ws + 4718592);       // 4 MB    [4][64][8192] bf16
  float*    f1   = (float*)   (ws + 8912896);       // 128 KB  (pre-scaled by log2e)
  float*    f2   = (float*)   (ws + 9043968);       // 128 KB
  float*    accA = (float*)   (ws + 9175040);       // 34.08 MB [4][8192][260]
  uint16_t* xcat = (uint16_t*)(ws + 43253760);      // 4 MB    [8192][256] bf16
  uint16_t* h2T  = (uint16_t*)(ws + 47448064);      // 256 KB  [16][8192] bf16
  float*    f1o  = (float*)   (ws + 47710208);      // 32 KB
  float*    f2o  = (float*)   (ws + 47742976);      // 32 KB
  float*    accB = (float*)   (ws + 47775744);      // 8 MB    [8][8192][32]
  void*     adjP = (void*)    (ws + 56164352);      // 8 MB    bitmask (end 64552960)

  hipLaunchKernelGGL(kp_pack,  dim3(2048), dim3(256), 0, stream, adj, (unsigned long long*)adjP);
  hipLaunchKernelGGL(k0_wht,   dim3(512),  dim3(256), 0, stream, Wh, WhT);
  hipLaunchKernelGGL(k1_h,     dim3(1024), dim3(256), 0, stream, x, WhT, ah, H, f1, f2);
  hipLaunchKernelGGL(k2a_htT,  dim3(512),  dim3(256), 0, stream, H, HT);
  hipLaunchKernelGGL(k3_attA,  dim3(512),  dim3(512), 0, stream, (const uint32_t*)adjP, HT, f1, f2, accA);
  hipLaunchKernelGGL(k4_redA,  dim3(8192), dim3(256), 0, stream, accA, xcat);
  hipLaunchKernelGGL(k5_h2,    dim3(512),  dim3(256), 0, stream, xcat, Wo, ao, h2T, f1o, f2o);
  hipLaunchKernelGGL(k6_attB,  dim3(1024), dim3(256), 0, stream, (const uint32_t*)adjP, h2T, f1o, f2o, accB);
  hipLaunchKernelGGL(k7_redB,  dim3(512),  dim3(256), 0, stream, accB, out);
}